// Round 7
// baseline (29.904 us; speedup 1.0000x reference)
//
#include <hip/hip_runtime.h>

#define NATOMS 4096
#define MAXP   32768
#define CUTOFF 5.0f
#define NBLK   1024
#define TPB    256
#define WPB    4               // rows (waves) per block
#define SPT    4               // state slots per thread (1024/256)

typedef unsigned long long u64;

__device__ __forceinline__ unsigned tag_of(int q) { return 0x9E3779B9u ^ (unsigned)q; }

// Scalar fallback: exact pair count for block q's 4 rows (identical FP order).
__device__ int count_rows_scalar(const float* __restrict__ pos,
                                 const int*   __restrict__ batch, int r0) {
#pragma clang fp contract(off)
    int c = 0;
    for (int i = r0; i < r0 + WPB; ++i) {
        const int b = batch[i];
        const float xi = pos[3*i], yi = pos[3*i+1], zi = pos[3*i+2];
        for (int j = i + 1; j < NATOMS; ++j) {
            if (batch[j] != b) break;
            float vx = xi - pos[3*j], vy = yi - pos[3*j+1], vz = zi - pos[3*j+2];
            float d2 = vx*vx + vy*vy + vz*vz;
            if (sqrtf(d2) < CUTOFF) ++c;
        }
    }
    return c;
}

__global__ __launch_bounds__(TPB, 4)
void fused_k(const float* __restrict__ pos,
             const int*   __restrict__ batch,
             u64*         __restrict__ state,
             float*       __restrict__ out) {
#pragma clang fp contract(off)
    const int tid  = threadIdx.x;
    const int p    = blockIdx.x;
    const int w    = tid >> 6;
    const int lane = tid & 63;
    const int i    = p * WPB + w;          // row owned by this wave

    const int b = batch[i];
    const float xi = pos[3*i], yi = pos[3*i+1], zi = pos[3*i+2];

    // ---- Phase A: count this wave's row ----
    int c = 0;
    for (int j0 = i + 1; j0 < NATOMS; j0 += 64) {
        int j = j0 + lane;
        bool in = j < NATOMS;
        int bj = in ? batch[j] : -1;
        bool same = in && (bj == b);
        bool valid = false;
        if (same) {
            float vx = xi - pos[3*j], vy = yi - pos[3*j+1], vz = zi - pos[3*j+2];
            float d2 = vx*vx + vy*vy + vz*vz;
            valid = sqrtf(d2) < CUTOFF;
        }
        c += __popcll(__ballot(valid));
        if (__any(in && (bj != b))) break;
    }

    // ---- publish block aggregate (payload packed in one 64-bit atom) ----
    __shared__ int ls[WPB];
    __shared__ int rt[TPB], rp[TPB];
    if (lane == 0) ls[w] = c;
    __syncthreads();
    if (tid == 0) {
        unsigned agg = (unsigned)(ls[0] + ls[1] + ls[2] + ls[3]);
        __hip_atomic_store(&state[p], ((u64)tag_of(p) << 32) | agg,
                           __ATOMIC_RELEASE, __HIP_MEMORY_SCOPE_AGENT);
    }

    // ---- all-thread scan: each thread owns 4 state slots ----
    const int base = tid * SPT;
    u64 v[SPT];
#pragma unroll
    for (int e = 0; e < SPT; ++e)
        v[e] = __hip_atomic_load(&state[base + e], __ATOMIC_RELAXED,
                                 __HIP_MEMORY_SCOPE_AGENT);
    for (int it = 0; it < 20000; ++it) {
        bool ok = true;
#pragma unroll
        for (int e = 0; e < SPT; ++e) {
            if ((unsigned)(v[e] >> 32) != tag_of(base + e)) {
                v[e] = __hip_atomic_load(&state[base + e], __ATOMIC_RELAXED,
                                         __HIP_MEMORY_SCOPE_AGENT);
                if ((unsigned)(v[e] >> 32) != tag_of(base + e)) ok = false;
            }
        }
        if (ok) break;
    }
#pragma unroll
    for (int e = 0; e < SPT; ++e) {   // bounded fallback (co-residency pathology)
        if ((unsigned)(v[e] >> 32) != tag_of(base + e))
            v[e] = ((u64)tag_of(base + e) << 32) |
                   (unsigned)count_rows_scalar(pos, batch, (base + e) * WPB);
    }
    int tsum = 0, psum = 0;
#pragma unroll
    for (int e = 0; e < SPT; ++e) {
        int a = (int)(v[e] & 0xffffffffULL);
        tsum += a;
        if (base + e < p) psum += a;
    }
    rt[tid] = tsum; rp[tid] = psum;
    __syncthreads();
    for (int s = 128; s > 0; s >>= 1) {
        if (tid < s) { rt[tid] += rt[tid + s]; rp[tid] += rp[tid + s]; }
        __syncthreads();
    }
    const int total = rt[0];
    int rowbase = rp[0];
    for (int r = 0; r < w; ++r) rowbase += ls[r];

    // ---- tail fill [total, MAXP): disjoint from all pair slots ----
    {
        int t = total + p * TPB + tid;
        if (t < MAXP) {
            out[t]          = -1.0f;
            out[MAXP + t]   = -1.0f;
            out[2*MAXP + t] =  0.0f;
            float* vv = out + 3*MAXP + 3*t;
            vv[0] = 0.f; vv[1] = 0.f; vv[2] = 0.f;
        }
    }

    // ---- Phase B: recompute pairs (identical order) and write ----
    int slotbase = rowbase;
    for (int j0 = i + 1; j0 < NATOMS; j0 += 64) {
        int j = j0 + lane;
        bool in = j < NATOMS;
        int bj = in ? batch[j] : -1;
        bool same = in && (bj == b);
        float vx = 0.f, vy = 0.f, vz = 0.f, d = 0.f;
        bool valid = false;
        if (same) {
            vx = xi - pos[3*j]; vy = yi - pos[3*j+1]; vz = zi - pos[3*j+2];
            float d2 = vx*vx + vy*vy + vz*vz;
            d = sqrtf(d2);
            valid = d < CUTOFF;
        }
        u64 m = __ballot(valid);
        if (valid) {
            int slot = slotbase + __popcll(m & ((1ULL << lane) - 1ULL));
            if (slot < MAXP) {
                out[slot]          = (float)i;   // neighbors[0, slot]
                out[MAXP + slot]   = (float)j;   // neighbors[1, slot]
                out[2*MAXP + slot] = d;          // distances[slot]
                float* vv = out + 3*MAXP + 3*slot;
                vv[0] = vx; vv[1] = vy; vv[2] = vz;
            }
        }
        slotbase += __popcll(m);
        if (__any(in && (bj != b))) break;
    }
}

extern "C" void kernel_launch(void* const* d_in, const int* in_sizes, int n_in,
                              void* d_out, int out_size, void* d_ws, size_t ws_size,
                              hipStream_t stream) {
    const float* pos   = (const float*)d_in[0];   // [4096,3] f32
    const int*   batch = (const int*)d_in[1];     // [4096] i32 (sorted)
    float* out   = (float*)d_out;                 // 196608 f32 (all outputs)
    u64*   state = (u64*)d_ws;                    // 1024 x u64 publish slots

    fused_k<<<NBLK, TPB, 0, stream>>>(pos, batch, state, out);
}

// Round 8
// 17.069 us; speedup vs baseline: 1.7519x; 1.7519x over previous
//
#include <hip/hip_runtime.h>

#define NATOMS 4096
#define MAXP   32768
#define CUTOFF 5.0f
#define NBLK   1024
#define TPB    256
#define WPB    4               // rows (waves) per block
#define PSTRIDE 32             // cached pairs per row (SoA)
#define PF      (PSTRIDE * 5)  // floats per row: j,d,vx,vy,vz fields

typedef unsigned long long u64;

// ---------------------------------------------------------------------------
// K1: per-row count + SoA pair cache. One wave per row. batch/pos loads are
// unconditional (j<NATOMS only) so the two chains issue in parallel.
// ---------------------------------------------------------------------------
__global__ __launch_bounds__(TPB)
void count_k(const float* __restrict__ pos,
             const int*   __restrict__ batch,
             int*         __restrict__ cnt,
             int*         __restrict__ bsum,
             float*       __restrict__ pair) {
#pragma clang fp contract(off)
    const int tid  = threadIdx.x;
    const int p    = blockIdx.x;
    const int w    = tid >> 6;
    const int lane = tid & 63;
    const int i    = p * WPB + w;

    const int b = batch[i];
    const float xi = pos[3*i], yi = pos[3*i+1], zi = pos[3*i+2];
    float* rowp = pair + (size_t)i * PF;

    int c = 0;
    for (int j0 = i + 1; j0 < NATOMS; j0 += 64) {
        int j = j0 + lane;
        bool in = j < NATOMS;
        int bj = -1;
        float px = 0.f, py = 0.f, pz = 0.f;
        if (in) {                       // independent loads, issued together
            bj = batch[j];
            px = pos[3*j]; py = pos[3*j+1]; pz = pos[3*j+2];
        }
        float vx = xi - px, vy = yi - py, vz = zi - pz;
        float d2 = vx*vx + vy*vy + vz*vz;
        float d  = sqrtf(d2);
        bool valid = in && (bj == b) && (d < CUTOFF);
        u64 m = __ballot(valid);
        if (valid) {
            int r = c + __popcll(m & ((1ULL << lane) - 1ULL));
            if (r < PSTRIDE) {          // SoA: coalesced per-field
                rowp[r]             = (float)j;
                rowp[PSTRIDE + r]   = d;
                rowp[2*PSTRIDE + r] = vx;
                rowp[3*PSTRIDE + r] = vy;
                rowp[4*PSTRIDE + r] = vz;
            }
        }
        c += __popcll(m);
        if (__any(in && (bj != b))) break;   // batch sorted: row ended
    }

    __shared__ int ls[WPB];
    if (lane == 0) { cnt[i] = c; ls[w] = c; }
    __syncthreads();
    if (tid == 0) bsum[p] = ls[0] + ls[1] + ls[2] + ls[3];
}

// ---------------------------------------------------------------------------
// K2: wave-0 packed (total | prefix<p) reduce over bsum, tail fill
// [total, MAXP), then single-pass coalesced copy of cached pairs.
// ---------------------------------------------------------------------------
__global__ __launch_bounds__(TPB)
void write_k(const float* __restrict__ pos,
             const int*   __restrict__ batch,
             const int*   __restrict__ cnt,
             const int*   __restrict__ bsum,
             const float* __restrict__ pair,
             float*       __restrict__ out) {
#pragma clang fp contract(off)
    const int tid  = threadIdx.x;
    const int p    = blockIdx.x;
    const int w    = tid >> 6;
    const int lane = tid & 63;
    const int i    = p * WPB + w;

    __shared__ int ls[WPB];
    __shared__ int s_pfx, s_total;

    const int c = cnt[i];
    if (lane == 0) ls[w] = c;

    if (w == 0) {
        u64 acc = 0;                      // (total << 32) | prefix_{q<p}
        for (int q = lane; q < NBLK; q += 64) {
            u64 a = (unsigned)bsum[q];
            acc += (a << 32) | (q < p ? a : 0ULL);
        }
        for (int o = 32; o; o >>= 1) acc += __shfl_down(acc, o);
        if (lane == 0) { s_total = (int)(acc >> 32); s_pfx = (int)acc; }
    }
    __syncthreads();

    const int total = s_total;
    int rowbase = s_pfx;
    for (int r = 0; r < w; ++r) rowbase += ls[r];

    // ---- tail fill [total, MAXP): disjoint from all pair slots ----
    {
        int t = total + p * TPB + tid;
        if (t < MAXP) {
            out[t]          = -1.0f;
            out[MAXP + t]   = -1.0f;
            out[2*MAXP + t] =  0.0f;
            float* vv = out + 3*MAXP + 3*t;
            vv[0] = 0.f; vv[1] = 0.f; vv[2] = 0.f;
        }
    }

    if (c <= PSTRIDE) {
        const float* rowp = pair + (size_t)i * PF;
        if (lane < c) {                   // c <= 32: single pass
            int slot = rowbase + lane;
            if (slot < MAXP) {
                out[slot]          = (float)i;              // neighbors[0]
                out[MAXP + slot]   = rowp[lane];            // neighbors[1]
                out[2*MAXP + slot] = rowp[PSTRIDE + lane];  // distances
                float* vv = out + 3*MAXP + 3*slot;
                vv[0] = rowp[2*PSTRIDE + lane];
                vv[1] = rowp[3*PSTRIDE + lane];
                vv[2] = rowp[4*PSTRIDE + lane];
            }
        }
    } else {
        // pathological row (> PSTRIDE pairs): recompute, identical order
        const int b = batch[i];
        const float xi = pos[3*i], yi = pos[3*i+1], zi = pos[3*i+2];
        int slotbase = rowbase;
        for (int j0 = i + 1; j0 < NATOMS; j0 += 64) {
            int j = j0 + lane;
            bool in = j < NATOMS;
            int bj = -1;
            float px = 0.f, py = 0.f, pz = 0.f;
            if (in) {
                bj = batch[j];
                px = pos[3*j]; py = pos[3*j+1]; pz = pos[3*j+2];
            }
            float vx = xi - px, vy = yi - py, vz = zi - pz;
            float d2 = vx*vx + vy*vy + vz*vz;
            float d  = sqrtf(d2);
            bool valid = in && (bj == b) && (d < CUTOFF);
            u64 m = __ballot(valid);
            if (valid) {
                int slot = slotbase + __popcll(m & ((1ULL << lane) - 1ULL));
                if (slot < MAXP) {
                    out[slot]          = (float)i;
                    out[MAXP + slot]   = (float)j;
                    out[2*MAXP + slot] = d;
                    float* vv = out + 3*MAXP + 3*slot;
                    vv[0] = vx; vv[1] = vy; vv[2] = vz;
                }
            }
            slotbase += __popcll(m);
            if (__any(in && (bj != b))) break;
        }
    }
}

extern "C" void kernel_launch(void* const* d_in, const int* in_sizes, int n_in,
                              void* d_out, int out_size, void* d_ws, size_t ws_size,
                              hipStream_t stream) {
    const float* pos   = (const float*)d_in[0];   // [4096,3] f32
    const int*   batch = (const int*)d_in[1];     // [4096] i32 (sorted)
    float* out = (float*)d_out;                   // 196608 f32 (all outputs)

    int*   cnt  = (int*)d_ws;                 // 4096 ints
    int*   bsum = cnt + NATOMS;               // 1024 ints
    float* pair = (float*)(bsum + NBLK);      // 4096 * 160 floats (~2.6 MB)

    count_k<<<NBLK, TPB, 0, stream>>>(pos, batch, cnt, bsum, pair);
    write_k<<<NBLK, TPB, 0, stream>>>(pos, batch, cnt, bsum, pair, out);
}

// Round 9
// 12.623 us; speedup vs baseline: 2.3689x; 1.3522x over previous
//
#include <hip/hip_runtime.h>

#define NATOMS 4096
#define MAXP   32768
#define CUTOFF 5.0f
#define OUT_TOTAL (6 * MAXP)   // 65536 neighbors + 32768 dist + 98304 vecs
#define NBLK   1024
#define TPB    256
#define WPB    4               // rows (waves) per block
#define PSTRIDE 64             // cached pairs per row (AoS, 5 floats each)
#define PF      (PSTRIDE * 5)

typedef unsigned long long u64;

// sum of the four 16-bit fields of x (each field < 4096, no carries)
__device__ __forceinline__ int field_sum(u64 x) {
    u64 s = x + (x >> 32);
    return (int)((s & 0xFFFFu) + ((s >> 16) & 0xFFFFu));
}

// ---------------------------------------------------------------------------
// K1: full output fill (overlapped) + per-row count + AoS pair cache.
// One wave per row; publishes 4x16-bit packed counts per block.
// ---------------------------------------------------------------------------
__global__ __launch_bounds__(TPB)
void count_k(const float* __restrict__ pos,
             const int*   __restrict__ batch,
             u64*         __restrict__ bsum,
             float*       __restrict__ pair,
             float*       __restrict__ out) {
#pragma clang fp contract(off)
    const int tid  = threadIdx.x;
    const int p    = blockIdx.x;
    const int w    = tid >> 6;
    const int lane = tid & 63;
    const int i    = p * WPB + w;

    // --- fill slice: 1024 blocks * 256 threads = 262144 >= 196608 ---
    {
        int idx = p * TPB + tid;
        if (idx < OUT_TOTAL) out[idx] = (idx < 2 * MAXP) ? -1.0f : 0.0f;
    }

    const int b = batch[i];
    const float xi = pos[3*i], yi = pos[3*i+1], zi = pos[3*i+2];
    float* rowp = pair + (size_t)i * PF;

    int c = 0;
    for (int j0 = i + 1; j0 < NATOMS; j0 += 64) {
        int j = j0 + lane;
        bool in = j < NATOMS;
        int bj = in ? batch[j] : -1;
        bool same = in && (bj == b);
        float vx = 0.f, vy = 0.f, vz = 0.f, d = 0.f;
        bool valid = false;
        if (same) {
            vx = xi - pos[3*j]; vy = yi - pos[3*j+1]; vz = zi - pos[3*j+2];
            float d2 = vx*vx + vy*vy + vz*vz;
            d = sqrtf(d2);
            valid = d < CUTOFF;
        }
        u64 m = __ballot(valid);
        if (valid) {
            int r = c + __popcll(m & ((1ULL << lane) - 1ULL));
            if (r < PSTRIDE) {
                float* q = rowp + r * 5;
                q[0] = (float)j; q[1] = d; q[2] = vx; q[3] = vy; q[4] = vz;
            }
        }
        c += __popcll(m);
        if (__any(in && (bj != b))) break;   // batch sorted: row ended
    }

    __shared__ int ls[WPB];
    if (lane == 0) ls[w] = c;
    __syncthreads();
    if (tid == 0)
        bsum[p] = (u64)(unsigned)ls[0]        | ((u64)(unsigned)ls[1] << 16) |
                 ((u64)(unsigned)ls[2] << 32) | ((u64)(unsigned)ls[3] << 48);
}

// ---------------------------------------------------------------------------
// K2: distributed prefix scan over packed counts + coalesced pair copy.
// ---------------------------------------------------------------------------
__global__ __launch_bounds__(TPB)
void write_k(const float* __restrict__ pos,
             const int*   __restrict__ batch,
             const u64*   __restrict__ bsum,
             const float* __restrict__ pair,
             float*       __restrict__ out) {
#pragma clang fp contract(off)
    const int tid  = threadIdx.x;
    const int p    = blockIdx.x;
    const int w    = tid >> 6;
    const int lane = tid & 63;
    const int i    = p * WPB + w;

    // --- prefix_{q<p}: 4 slots/thread, independent loads, shfl+LDS reduce ---
    int partial = 0;
#pragma unroll
    for (int e = 0; e < 4; ++e) {
        int q = tid * 4 + e;
        if (q < p) partial += field_sum(bsum[q]);
    }
    for (int o = 32; o; o >>= 1) partial += __shfl_down(partial, o);
    __shared__ int lpart[WPB];
    if (lane == 0) lpart[w] = partial;
    __syncthreads();
    const int prefix = lpart[0] + lpart[1] + lpart[2] + lpart[3];

    // --- own-block row counts from one packed word ---
    const u64 bp = bsum[p];
    const int c  = (int)((bp >> (16 * w)) & 0xFFFFu);
    int rowbase = prefix;
    for (int r = 0; r < w; ++r) rowbase += (int)((bp >> (16 * r)) & 0xFFFFu);

    if (c <= PSTRIDE) {
        const float* rowp = pair + (size_t)i * PF;
        if (lane < c) {                       // c <= 64: single pass
            int slot = rowbase + lane;
            if (slot < MAXP) {
                const float* q = rowp + lane * 5;
                out[slot]          = (float)i;   // neighbors[0, slot]
                out[MAXP + slot]   = q[0];       // neighbors[1, slot] (= j)
                out[2*MAXP + slot] = q[1];       // distances[slot]
                float* vv = out + 3*MAXP + 3*slot;
                vv[0] = q[2]; vv[1] = q[3]; vv[2] = q[4];
            }
        }
    } else {
        // pathological row (> PSTRIDE pairs): recompute, identical FP order
        const int b = batch[i];
        const float xi = pos[3*i], yi = pos[3*i+1], zi = pos[3*i+2];
        int slotbase = rowbase;
        for (int j0 = i + 1; j0 < NATOMS; j0 += 64) {
            int j = j0 + lane;
            bool in = j < NATOMS;
            int bj = in ? batch[j] : -1;
            bool same = in && (bj == b);
            float vx = 0.f, vy = 0.f, vz = 0.f, d = 0.f;
            bool valid = false;
            if (same) {
                vx = xi - pos[3*j]; vy = yi - pos[3*j+1]; vz = zi - pos[3*j+2];
                float d2 = vx*vx + vy*vy + vz*vz;
                d = sqrtf(d2);
                valid = d < CUTOFF;
            }
            u64 m = __ballot(valid);
            if (valid) {
                int slot = slotbase + __popcll(m & ((1ULL << lane) - 1ULL));
                if (slot < MAXP) {
                    out[slot]          = (float)i;
                    out[MAXP + slot]   = (float)j;
                    out[2*MAXP + slot] = d;
                    float* vv = out + 3*MAXP + 3*slot;
                    vv[0] = vx; vv[1] = vy; vv[2] = vz;
                }
            }
            slotbase += __popcll(m);
            if (__any(in && (bj != b))) break;
        }
    }
}

extern "C" void kernel_launch(void* const* d_in, const int* in_sizes, int n_in,
                              void* d_out, int out_size, void* d_ws, size_t ws_size,
                              hipStream_t stream) {
    const float* pos   = (const float*)d_in[0];   // [4096,3] f32
    const int*   batch = (const int*)d_in[1];     // [4096] i32 (sorted)
    float* out = (float*)d_out;                   // 196608 f32 (all outputs)

    u64*   bsum = (u64*)d_ws;                 // 1024 packed count words
    float* pair = (float*)(bsum + NBLK);      // 4096 * 320 floats (~5.2 MB)

    count_k<<<NBLK, TPB, 0, stream>>>(pos, batch, bsum, pair, out);
    write_k<<<NBLK, TPB, 0, stream>>>(pos, batch, bsum, pair, out);
}

// Round 10
// 12.568 us; speedup vs baseline: 2.3793x; 1.0044x over previous
//
#include <hip/hip_runtime.h>

#define NATOMS 4096
#define MAXP   32768
#define CUTOFF 5.0f
#define OUT_TOTAL (6 * MAXP)   // 65536 neighbors + 32768 dist + 98304 vecs
#define NBLK   1024
#define TPB    256
#define WPB    4               // rows (waves) per block
#define PSTRIDE 64             // cached pairs per row
#define PQ      8              // floats per pair record (5 used, padded to 8)
#define PF      (PSTRIDE * PQ)

typedef unsigned long long u64;

// sum of the four 16-bit fields of x (each field < 4096, no carries)
__device__ __forceinline__ int field_sum(u64 x) {
    u64 s = x + (x >> 32);
    return (int)((s & 0xFFFFu) + ((s >> 16) & 0xFFFFu));
}

// ---------------------------------------------------------------------------
// K1: full output fill (overlapped) + per-row count + AoS(pad8) pair cache.
// One wave per row. 2-chunk unrolled: all loads for 128 atoms issue up-front,
// collapsing the chunk-serial dependency chain. Lanes past the molecule
// boundary can never be valid (bj != b), so no early-exit precision issues.
// ---------------------------------------------------------------------------
__global__ __launch_bounds__(TPB)
void count_k(const float* __restrict__ pos,
             const int*   __restrict__ batch,
             u64*         __restrict__ bsum,
             float*       __restrict__ pair,
             float*       __restrict__ out) {
#pragma clang fp contract(off)
    const int tid  = threadIdx.x;
    const int p    = blockIdx.x;
    const int w    = tid >> 6;
    const int lane = tid & 63;
    const int i    = p * WPB + w;

    // --- fill slice: 1024 blocks * 256 threads = 262144 >= 196608 ---
    {
        int idx = p * TPB + tid;
        if (idx < OUT_TOTAL) out[idx] = (idx < 2 * MAXP) ? -1.0f : 0.0f;
    }

    const int b = batch[i];
    const float xi = pos[3*i], yi = pos[3*i+1], zi = pos[3*i+2];
    float* rowp = pair + (size_t)i * PF;

    int c = 0;
    for (int j0 = i + 1; j0 < NATOMS; j0 += 128) {
        const int jA = j0 + lane;
        const int jB = jA + 64;
        const bool inA = jA < NATOMS;
        const bool inB = jB < NATOMS;
        // issue ALL loads up front (independent; masked lanes load nothing)
        int bA = -1, bB = -1;
        float axp = 0.f, ayp = 0.f, azp = 0.f;
        float bxp = 0.f, byp = 0.f, bzp = 0.f;
        if (inA) { bA = batch[jA]; axp = pos[3*jA]; ayp = pos[3*jA+1]; azp = pos[3*jA+2]; }
        if (inB) { bB = batch[jB]; bxp = pos[3*jB]; byp = pos[3*jB+1]; bzp = pos[3*jB+2]; }

        // chunk A
        {
            float vx = xi - axp, vy = yi - ayp, vz = zi - azp;
            float d2 = vx*vx + vy*vy + vz*vz;
            float d  = sqrtf(d2);
            bool valid = inA && (bA == b) && (d < CUTOFF);
            u64 m = __ballot(valid);
            if (valid) {
                int r = c + __popcll(m & ((1ULL << lane) - 1ULL));
                if (r < PSTRIDE) {
                    float* q = rowp + r * PQ;
                    q[0] = (float)jA; q[1] = d; q[2] = vx; q[3] = vy; q[4] = vz;
                }
            }
            c += __popcll(m);
        }
        // chunk B
        {
            float vx = xi - bxp, vy = yi - byp, vz = zi - bzp;
            float d2 = vx*vx + vy*vy + vz*vz;
            float d  = sqrtf(d2);
            bool valid = inB && (bB == b) && (d < CUTOFF);
            u64 m = __ballot(valid);
            if (valid) {
                int r = c + __popcll(m & ((1ULL << lane) - 1ULL));
                if (r < PSTRIDE) {
                    float* q = rowp + r * PQ;
                    q[0] = (float)jB; q[1] = d; q[2] = vx; q[3] = vy; q[4] = vz;
                }
            }
            c += __popcll(m);
        }
        // row ended inside this 128-wide window? (batch sorted)
        if (__any((inA && (bA != b)) || (inB && (bB != b)))) break;
    }

    __shared__ int ls[WPB];
    if (lane == 0) ls[w] = c;
    __syncthreads();
    if (tid == 0)
        bsum[p] = (u64)(unsigned)ls[0]        | ((u64)(unsigned)ls[1] << 16) |
                 ((u64)(unsigned)ls[2] << 32) | ((u64)(unsigned)ls[3] << 48);
}

// ---------------------------------------------------------------------------
// K2: distributed prefix scan over packed counts + aligned pair copy.
// ---------------------------------------------------------------------------
__global__ __launch_bounds__(TPB)
void write_k(const float* __restrict__ pos,
             const int*   __restrict__ batch,
             const u64*   __restrict__ bsum,
             const float* __restrict__ pair,
             float*       __restrict__ out) {
#pragma clang fp contract(off)
    const int tid  = threadIdx.x;
    const int p    = blockIdx.x;
    const int w    = tid >> 6;
    const int lane = tid & 63;
    const int i    = p * WPB + w;

    const u64 bp = bsum[p];           // own-block packed counts (hoisted)

    // --- prefix_{q<p}: 4 slots/thread, independent loads, shfl+LDS reduce ---
    int partial = 0;
#pragma unroll
    for (int e = 0; e < 4; ++e) {
        int q = tid * 4 + e;
        if (q < p) partial += field_sum(bsum[q]);
    }
    for (int o = 32; o; o >>= 1) partial += __shfl_down(partial, o);
    __shared__ int lpart[WPB];
    if (lane == 0) lpart[w] = partial;
    __syncthreads();
    const int prefix = lpart[0] + lpart[1] + lpart[2] + lpart[3];

    const int c = (int)((bp >> (16 * w)) & 0xFFFFu);
    int rowbase = prefix;
    for (int r = 0; r < w; ++r) rowbase += (int)((bp >> (16 * r)) & 0xFFFFu);

    if (c <= PSTRIDE) {
        const float* rowp = pair + (size_t)i * PF;
        if (lane < c) {                       // c <= 64: single pass
            int slot = rowbase + lane;
            if (slot < MAXP) {
                const float* q = rowp + lane * PQ;   // 32B-aligned record
                out[slot]          = (float)i;   // neighbors[0, slot]
                out[MAXP + slot]   = q[0];       // neighbors[1, slot] (= j)
                out[2*MAXP + slot] = q[1];       // distances[slot]
                float* vv = out + 3*MAXP + 3*slot;
                vv[0] = q[2]; vv[1] = q[3]; vv[2] = q[4];
            }
        }
    } else {
        // pathological row (> PSTRIDE pairs): recompute, identical FP order
        const int b = batch[i];
        const float xi = pos[3*i], yi = pos[3*i+1], zi = pos[3*i+2];
        int slotbase = rowbase;
        for (int j0 = i + 1; j0 < NATOMS; j0 += 64) {
            int j = j0 + lane;
            bool in = j < NATOMS;
            int bj = in ? batch[j] : -1;
            bool same = in && (bj == b);
            float vx = 0.f, vy = 0.f, vz = 0.f, d = 0.f;
            bool valid = false;
            if (same) {
                vx = xi - pos[3*j]; vy = yi - pos[3*j+1]; vz = zi - pos[3*j+2];
                float d2 = vx*vx + vy*vy + vz*vz;
                d = sqrtf(d2);
                valid = d < CUTOFF;
            }
            u64 m = __ballot(valid);
            if (valid) {
                int slot = slotbase + __popcll(m & ((1ULL << lane) - 1ULL));
                if (slot < MAXP) {
                    out[slot]          = (float)i;
                    out[MAXP + slot]   = (float)j;
                    out[2*MAXP + slot] = d;
                    float* vv = out + 3*MAXP + 3*slot;
                    vv[0] = vx; vv[1] = vy; vv[2] = vz;
                }
            }
            slotbase += __popcll(m);
            if (__any(in && (bj != b))) break;
        }
    }
}

extern "C" void kernel_launch(void* const* d_in, const int* in_sizes, int n_in,
                              void* d_out, int out_size, void* d_ws, size_t ws_size,
                              hipStream_t stream) {
    const float* pos   = (const float*)d_in[0];   // [4096,3] f32
    const int*   batch = (const int*)d_in[1];     // [4096] i32 (sorted)
    float* out = (float*)d_out;                   // 196608 f32 (all outputs)

    u64*   bsum = (u64*)d_ws;                 // 1024 packed count words
    float* pair = (float*)(bsum + NBLK);      // 4096 * 512 floats (8 MB)

    count_k<<<NBLK, TPB, 0, stream>>>(pos, batch, bsum, pair, out);
    write_k<<<NBLK, TPB, 0, stream>>>(pos, batch, bsum, pair, out);
}